// Round 3
// baseline (1252.999 us; speedup 1.0000x reference)
//
#include <hip/hip_runtime.h>
#include <math.h>

#define BTOT 262144
#define FDIM 256
#define KK 20
#define HH 64
#define MM 32

#define IMP_OFF  (BTOT * KK)            // 5242880
#define CWM_OFF  (IMP_OFF + KK)         // 5242900
#define ACT_OFF  (CWM_OFF + KK)         // 5242920
#define PAIR_OFF (ACT_OFF + 1)          // 5242921

__device__ __forceinline__ bool better(float v2, int p2, float v1, int p1) {
  return (v2 > v1) || (v2 == v1 && p2 < p1);
}

// ---------------- Top-K stage 1: per-row top-20 ----------------
__global__ void topk_stage1(const float* __restrict__ w,
                            float* __restrict__ cand_v, int* __restrict__ cand_p) {
  const int i = blockIdx.x;
  const int j = threadIdx.x;
  const int lane = j & 63, wid = j >> 6;
  __shared__ float sv[256];
  __shared__ float rv[4];
  __shared__ int rp[4];

  sv[j] = (j > i) ? w[i * 256 + j] : -1e30f;
  __syncthreads();

  for (int r = 0; r < 20; ++r) {
    float v = sv[j];
    int p = i * 256 + j;
    #pragma unroll
    for (int off = 32; off; off >>= 1) {
      float v2 = __shfl_down(v, off);
      int p2 = __shfl_down(p, off);
      if (better(v2, p2, v, p)) { v = v2; p = p2; }
    }
    if (lane == 0) { rv[wid] = v; rp[wid] = p; }
    __syncthreads();
    if (j == 0) {
      #pragma unroll
      for (int t = 1; t < 4; ++t)
        if (better(rv[t], rp[t], v, p)) { v = rv[t]; p = rp[t]; }
      cand_v[i * 20 + r] = v;
      cand_p[i * 20 + r] = p;
      sv[p & 255] = -2e30f;
    }
    __syncthreads();
  }
}

// ---------------- Top-K stage 2: merge 256*20 candidates ----------------
#define NC 5120
__global__ void topk_stage2(const float* __restrict__ cand_v, const int* __restrict__ cand_p,
                            int* __restrict__ pij, float* __restrict__ out) {
  const int tid = threadIdx.x;
  const int lane = tid & 63, wid = tid >> 6;
  __shared__ float sv[NC];
  __shared__ int sp[NC];
  __shared__ float rv[4];
  __shared__ int rp[4], rq[4];
  __shared__ float selv[20];
  __shared__ int selp[20];

  for (int t = tid; t < NC; t += 256) { sv[t] = cand_v[t]; sp[t] = cand_p[t]; }
  __syncthreads();

  for (int r = 0; r < 20; ++r) {
    float v = -4e30f;
    int p = 0x7fffffff, q = 0;
    for (int t = tid; t < NC; t += 256) {
      float vv = sv[t];
      int pp = sp[t];
      if (better(vv, pp, v, p)) { v = vv; p = pp; q = t; }
    }
    #pragma unroll
    for (int off = 32; off; off >>= 1) {
      float v2 = __shfl_down(v, off);
      int p2 = __shfl_down(p, off);
      int q2 = __shfl_down(q, off);
      if (better(v2, p2, v, p)) { v = v2; p = p2; q = q2; }
    }
    if (lane == 0) { rv[wid] = v; rp[wid] = p; rq[wid] = q; }
    __syncthreads();
    if (tid == 0) {
      #pragma unroll
      for (int t = 1; t < 4; ++t)
        if (better(rv[t], rp[t], v, p)) { v = rv[t]; p = rp[t]; q = rq[t]; }
      selv[r] = v;
      selp[r] = p;
      sv[q] = -3e30f;
    }
    __syncthreads();
  }

  if (tid == 0) {
    int active = 0;
    for (int r = 0; r < 20; ++r) {
      int p = selp[r];
      int i = p >> 8, j = p & 255;
      float s = 1.0f / (1.0f + expf(-selv[r]));
      out[IMP_OFF + r] = s;
      out[PAIR_OFF + 2 * r] = (float)i;
      out[PAIR_OFF + 2 * r + 1] = (float)j;
      if (s > 0.1f) active++;
      pij[r] = i;
      pij[20 + r] = j;
    }
    out[ACT_OFF] = (float)active;
  }
}

// ================= Split path (round 3: scalar-pipe weights) =================
// Principle: all weights are wave-uniform -> s_load (scalar cache), costing
// ZERO VALU/LDS bandwidth. Round-2's LDS-broadcast b128 reads saturated the
// CU-wide LDS return path (id_pair VALUBusy 47%). Per-lane data (x rows,
// pv/ctx) comes via global vector loads (vmcnt) so the s_load stream's
// lgkmcnt pipelining is never drained by ds_reads in the hot loops.

// ---- id_ctx: x row in registers (line-exact per-thread loads); LDS used
// ONLY for the pair-column gather; Wc1/Wc2 via s_load. ----
#define FCH 32
#define NCH (FDIM / FCH)   // 8
#define XSTR 33            // gather stride: 33 coprime 32 -> conflict-free

__global__ __launch_bounds__(256, 4) void id_ctx(
    const float* __restrict__ x,
    const float* __restrict__ Wc1, const float* __restrict__ bc1,
    const float* __restrict__ Wc2, const float* __restrict__ bc2,
    const int* __restrict__ pij,
    float* __restrict__ pv_ws, float* __restrict__ ctx_ws,
    float* __restrict__ ctx_sums) {
  __shared__ __align__(16) float xs[256 * XSTR];   // 33792 B
  __shared__ float csum[KK];

  const int tid = threadIdx.x;
  const int b0 = blockIdx.x * 256;
  if (tid < KK) csum[tid] = 0.0f;

  int pcol[2 * KK];
  #pragma unroll
  for (int i = 0; i < 2 * KK; ++i) pcol[i] = __builtin_amdgcn_readfirstlane(pij[i]);

  float h[HH];
  #pragma unroll
  for (int j = 0; j < HH; ++j) h[j] = bc1[j];          // s_loads

  const float* __restrict__ xrow = x + (size_t)(b0 + tid) * FDIM;

  #pragma unroll 1
  for (int c = 0; c < NCH; ++c) {
    const int f0 = c * FCH;
    // own-row chunk: 8 float4 = one full 128B line + neighbor (line-exact, no waste)
    float4 xr[8];
    #pragma unroll
    for (int q = 0; q < 8; ++q) xr[q] = *(const float4*)(xrow + f0 + q * 4);

    __syncthreads();   // previous chunk's gather reads done
    #pragma unroll
    for (int q = 0; q < 8; ++q) *(float4*)&xs[tid * XSTR + q * 4] = xr[q];
    __syncthreads();   // xs visible

    // pair-column gather (uniform branch; ds_read_b32 stride 132B conflict-free)
    #pragma unroll
    for (int i = 0; i < 2 * KK; ++i) {
      const int cc = pcol[i];
      if (cc >= f0 && cc < f0 + FCH)
        pv_ws[(size_t)i * BTOT + b0 + tid] = xs[tid * XSTR + (cc - f0)];
    }

    // ctx hidden layer: xv from REGISTERS (static index), weights via s_load
    const float xv[FCH] = {
      xr[0].x, xr[0].y, xr[0].z, xr[0].w,  xr[1].x, xr[1].y, xr[1].z, xr[1].w,
      xr[2].x, xr[2].y, xr[2].z, xr[2].w,  xr[3].x, xr[3].y, xr[3].z, xr[3].w,
      xr[4].x, xr[4].y, xr[4].z, xr[4].w,  xr[5].x, xr[5].y, xr[5].z, xr[5].w,
      xr[6].x, xr[6].y, xr[6].z, xr[6].w,  xr[7].x, xr[7].y, xr[7].z, xr[7].w };
    #pragma unroll 4
    for (int f = 0; f < FCH; ++f) {
      const float xvf = xv[f];
      const float* __restrict__ w0 = Wc1 + (size_t)(f0 + f) * HH;   // uniform
      #pragma unroll
      for (int j = 0; j < HH; ++j) h[j] = fmaf(xvf, w0[j], h[j]);
    }
  }

  // ---- ctx output layer: s_load weights, fully static h/ctx ----
  float ctx[KK];
  #pragma unroll
  for (int k = 0; k < KK; ++k) ctx[k] = bc2[k];
  #pragma unroll 4
  for (int j = 0; j < HH; ++j) {
    const float hj = fmaxf(h[j], 0.0f);
    const float* __restrict__ wrow = Wc2 + j * KK;                  // uniform
    #pragma unroll
    for (int k = 0; k < KK; ++k) ctx[k] = fmaf(hj, wrow[k], ctx[k]);
  }
  #pragma unroll
  for (int k = 0; k < KK; ++k) {
    ctx[k] = 1.0f / (1.0f + expf(-ctx[k]));
    ctx_ws[(size_t)k * BTOT + b0 + tid] = ctx[k];   // coalesced [k][B]
  }

  // ---- ctx mean: wave shuffle -> LDS -> global atomic ----
  const int lane = tid & 63;
  #pragma unroll
  for (int k = 0; k < KK; ++k) {
    float v = ctx[k];
    #pragma unroll
    for (int off = 32; off; off >>= 1) v += __shfl_down(v, off);
    if (lane == 0) atomicAdd(&csum[k], v);
  }
  __syncthreads();
  if (tid < KK) atomicAdd(&ctx_sums[tid], csum[tid]);
}

// ---- id_pair: NO LDS, NO barriers. Weights stream through the scalar pipe
// (s_load, scalar cache); per-sample pa/pb/ctx are coalesced global reads
// prefetched one k ahead. VALU-issue-bound target ~160-190 us. ----
__global__ __launch_bounds__(256, 4) void id_pair(
    const float* __restrict__ W1, const float* __restrict__ b1,
    const float* __restrict__ W2, const float* __restrict__ b2,
    const float* __restrict__ W3, const float* __restrict__ b3,
    const float* __restrict__ pv_ws, const float* __restrict__ ctx_ws,
    float* __restrict__ out) {
  const int tid = threadIdx.x;
  const size_t b = (size_t)blockIdx.x * 256 + tid;

  float pa   = pv_ws[b];
  float pb   = pv_ws[(size_t)KK * BTOT + b];
  float ctxk = ctx_ws[b];

  #pragma unroll 1
  for (int k = 0; k < KK; ++k) {
    const float* __restrict__ w1a = W1 + (size_t)k * 2 * HH;   // uniform -> s_load
    const float* __restrict__ w1b = w1a + HH;
    const float* __restrict__ b1k = b1 + (size_t)k * HH;
    const float* __restrict__ w2k = W2 + (size_t)k * HH * MM;
    const float* __restrict__ b2k = b2 + (size_t)k * MM;
    const float* __restrict__ w3k = W3 + (size_t)k * MM;

    float h2[MM];
    #pragma unroll
    for (int m = 0; m < MM; ++m) h2[m] = b2k[m];

    #pragma unroll 4
    for (int j = 0; j < HH; ++j) {
      const float h1 = fmaxf(fmaf(pa, w1a[j], fmaf(pb, w1b[j], b1k[j])), 0.0f);
      #pragma unroll
      for (int m = 0; m < MM; ++m) h2[m] = fmaf(h1, w2k[j * MM + m], h2[m]);
    }

    float o = b3[k];
    #pragma unroll
    for (int m = 0; m < MM; ++m) o = fmaf(fmaxf(h2[m], 0.0f), w3k[m], o);

    const float res = o * ctxk;
    if (k + 1 < KK) {      // prefetch next k's per-sample inputs (vmcnt-hidden)
      pa   = pv_ws[(size_t)(k + 1) * BTOT + b];
      pb   = pv_ws[(size_t)(KK + k + 1) * BTOT + b];
      ctxk = ctx_ws[(size_t)(k + 1) * BTOT + b];
    }
    out[b * KK + k] = res;
  }
}

// ================= Fallback fused kernel (round-1, known-passing) =================
#define FCHF 32
#define NCHUNKF (FDIM / FCHF)
#define XSTRF 33

__global__ __launch_bounds__(256, 3) void id_main_fused(
    const float* __restrict__ x,
    const float* __restrict__ Wc1, const float* __restrict__ bc1,
    const float* __restrict__ Wc2, const float* __restrict__ bc2,
    const float* __restrict__ W1, const float* __restrict__ b1,
    const float* __restrict__ W2, const float* __restrict__ b2,
    const float* __restrict__ W3, const float* __restrict__ b3,
    const int* __restrict__ pij,
    float* __restrict__ ctx_sums,
    float* __restrict__ out) {
  __shared__ __align__(16) float xs[256 * XSTRF];
  __shared__ float csum[KK];

  const int tid = threadIdx.x;
  const int b0 = blockIdx.x * 256;
  if (tid < KK) csum[tid] = 0.0f;

  int pcol[2 * KK];
  #pragma unroll
  for (int i = 0; i < 2 * KK; ++i) pcol[i] = __builtin_amdgcn_readfirstlane(pij[i]);

  float h[HH];
  #pragma unroll
  for (int j = 0; j < HH; ++j) h[j] = bc1[j];
  float pv[2 * KK];
  #pragma unroll
  for (int i = 0; i < 2 * KK; ++i) pv[i] = 0.0f;

  const int srow = tid >> 3;
  const int quad = tid & 7;
  const float* __restrict__ xrow_lds = &xs[tid * XSTRF];

  #pragma unroll 1
  for (int c = 0; c < NCHUNKF; ++c) {
    const int f0 = c * FCHF;
    __syncthreads();
    const float* __restrict__ xg = x + (size_t)(b0 + srow) * FDIM + f0 + quad * 4;
    #pragma unroll
    for (int r = 0; r < 8; ++r) {
      const float4 v = *(const float4*)(xg + (size_t)r * 32 * FDIM);
      float* d = &xs[(srow + r * 32) * XSTRF + quad * 4];
      d[0] = v.x; d[1] = v.y; d[2] = v.z; d[3] = v.w;
    }
    __syncthreads();
    #pragma unroll 2
    for (int f = 0; f < FCHF; ++f) {
      const float xv = xrow_lds[f];
      const float* __restrict__ w0 = Wc1 + (size_t)(f0 + f) * HH;
      #pragma unroll
      for (int j = 0; j < HH; ++j) h[j] = fmaf(xv, w0[j], h[j]);
    }
    #pragma unroll
    for (int i = 0; i < 2 * KK; ++i) {
      const int cc = pcol[i];
      if (cc >= f0 && cc < f0 + FCHF) pv[i] = xrow_lds[cc - f0];
    }
  }

  float ctx[KK];
  #pragma unroll
  for (int k = 0; k < KK; ++k) ctx[k] = bc2[k];
  #pragma unroll
  for (int j = 0; j < HH; ++j) {
    const float hj = fmaxf(h[j], 0.0f);
    const float* __restrict__ wr = Wc2 + j * KK;
    #pragma unroll
    for (int k = 0; k < KK; ++k) ctx[k] = fmaf(hj, wr[k], ctx[k]);
  }
  #pragma unroll
  for (int k = 0; k < KK; ++k) ctx[k] = 1.0f / (1.0f + expf(-ctx[k]));

  __syncthreads();
  float* __restrict__ so = xs;

  #pragma unroll 1
  for (int k = 0; k < KK; ++k) {
    float pa = 0.0f, pb = 0.0f;
    #pragma unroll
    for (int i = 0; i < KK; ++i)
      if (k == i) { pa = pv[i]; pb = pv[KK + i]; }

    const float* __restrict__ w1k = W1 + (size_t)k * 2 * HH;
    const float* __restrict__ b1k = b1 + (size_t)k * HH;
    const float* __restrict__ w2k = W2 + (size_t)k * HH * MM;
    const float* __restrict__ b2k = b2 + (size_t)k * MM;

    float h2[MM];
    #pragma unroll
    for (int m = 0; m < MM; ++m) h2[m] = b2k[m];

    #pragma unroll 2
    for (int j = 0; j < HH; ++j) {
      const float h1j = fmaxf(fmaf(pa, w1k[j], fmaf(pb, w1k[HH + j], b1k[j])), 0.0f);
      const float* __restrict__ wr = w2k + j * MM;
      #pragma unroll
      for (int m = 0; m < MM; ++m) h2[m] = fmaf(h1j, wr[m], h2[m]);
    }

    const float* __restrict__ w3k = W3 + (size_t)k * MM;
    float o = b3[k];
    #pragma unroll
    for (int m = 0; m < MM; ++m) o = fmaf(fmaxf(h2[m], 0.0f), w3k[m], o);

    so[tid * KK + k] = o;
  }

  #pragma unroll
  for (int k = 0; k < KK; ++k) so[tid * KK + k] *= ctx[k];

  const int lane = tid & 63;
  #pragma unroll
  for (int k = 0; k < KK; ++k) {
    float v = ctx[k];
    #pragma unroll
    for (int off = 32; off; off >>= 1) v += __shfl_down(v, off);
    if (lane == 0) atomicAdd(&csum[k], v);
  }
  __syncthreads();
  if (tid < KK) atomicAdd(&ctx_sums[tid], csum[tid]);

  const float4* __restrict__ sof = (const float4*)so;
  float4* __restrict__ og = (float4*)(out + (size_t)b0 * KK);
  #pragma unroll
  for (int i = 0; i < 5; ++i) og[tid + i * 256] = sof[tid + i * 256];
}

__global__ void id_finalize(const float* __restrict__ ctx_sums, float* __restrict__ out) {
  const int k = threadIdx.x;
  if (k < KK) out[CWM_OFF + k] = ctx_sums[k] * (1.0f / (float)BTOT);
}

extern "C" void kernel_launch(void* const* d_in, const int* in_sizes, int n_in,
                              void* d_out, int out_size, void* d_ws, size_t ws_size,
                              hipStream_t stream) {
  const float* x   = (const float*)d_in[0];
  const float* iw  = (const float*)d_in[1];
  const float* Wc1 = (const float*)d_in[2];
  const float* bc1 = (const float*)d_in[3];
  const float* Wc2 = (const float*)d_in[4];
  const float* bc2 = (const float*)d_in[5];
  const float* W1  = (const float*)d_in[6];
  const float* b1  = (const float*)d_in[7];
  const float* W2  = (const float*)d_in[8];
  const float* b2  = (const float*)d_in[9];
  const float* W3  = (const float*)d_in[10];
  const float* b3  = (const float*)d_in[11];
  float* out = (float*)d_out;

  float* wsf    = (float*)d_ws;
  float* cand_v = wsf;                  // 5120 floats
  int*   cand_p = (int*)(wsf + 5120);   // 5120 ints
  int*   pij    = (int*)(wsf + 10240);  // 40 ints
  float* csums  = wsf + 10280;          // 20 floats
  float* pv_ws  = wsf + 10304;          // 40*BTOT floats
  float* ctx_ws = wsf + 10304 + (size_t)2 * KK * BTOT;  // 20*BTOT floats
  const size_t need_bytes = ((size_t)10304 + (size_t)3 * KK * BTOT) * sizeof(float); // ~63 MB

  hipMemsetAsync(csums, 0, KK * sizeof(float), stream);
  topk_stage1<<<256, 256, 0, stream>>>(iw, cand_v, cand_p);
  topk_stage2<<<1, 256, 0, stream>>>(cand_v, cand_p, pij, out);
  if (ws_size >= need_bytes) {
    id_ctx<<<BTOT / 256, 256, 0, stream>>>(x, Wc1, bc1, Wc2, bc2, pij,
                                           pv_ws, ctx_ws, csums);
    id_pair<<<BTOT / 256, 256, 0, stream>>>(W1, b1, W2, b2, W3, b3,
                                            pv_ws, ctx_ws, out);
  } else {
    id_main_fused<<<BTOT / 256, 256, 0, stream>>>(x, Wc1, bc1, Wc2, bc2,
                                                  W1, b1, W2, b2, W3, b3,
                                                  pij, csums, out);
  }
  id_finalize<<<1, 64, 0, stream>>>(csums, out);
}

// Round 4
// 1067.139 us; speedup vs baseline: 1.1742x; 1.1742x over previous
//
#include <hip/hip_runtime.h>
#include <math.h>

#define BTOT 262144
#define FDIM 256
#define KK 20
#define HH 64
#define MM 32

#define IMP_OFF  (BTOT * KK)            // 5242880
#define CWM_OFF  (IMP_OFF + KK)         // 5242900
#define ACT_OFF  (CWM_OFF + KK)         // 5242920
#define PAIR_OFF (ACT_OFF + 1)          // 5242921

__device__ __forceinline__ bool better(float v2, int p2, float v1, int p1) {
  return (v2 > v1) || (v2 == v1 && p2 < p1);
}

// ---------------- Top-K stage 1: per-row top-20 ----------------
__global__ void topk_stage1(const float* __restrict__ w,
                            float* __restrict__ cand_v, int* __restrict__ cand_p) {
  const int i = blockIdx.x;
  const int j = threadIdx.x;
  const int lane = j & 63, wid = j >> 6;
  __shared__ float sv[256];
  __shared__ float rv[4];
  __shared__ int rp[4];

  sv[j] = (j > i) ? w[i * 256 + j] : -1e30f;
  __syncthreads();

  for (int r = 0; r < 20; ++r) {
    float v = sv[j];
    int p = i * 256 + j;
    #pragma unroll
    for (int off = 32; off; off >>= 1) {
      float v2 = __shfl_down(v, off);
      int p2 = __shfl_down(p, off);
      if (better(v2, p2, v, p)) { v = v2; p = p2; }
    }
    if (lane == 0) { rv[wid] = v; rp[wid] = p; }
    __syncthreads();
    if (j == 0) {
      #pragma unroll
      for (int t = 1; t < 4; ++t)
        if (better(rv[t], rp[t], v, p)) { v = rv[t]; p = rp[t]; }
      cand_v[i * 20 + r] = v;
      cand_p[i * 20 + r] = p;
      sv[p & 255] = -2e30f;
    }
    __syncthreads();
  }
}

// ---------------- Top-K stage 2: merge 256*20 candidates ----------------
// Also zeroes ctx_sums (replaces the hipMemsetAsync graph node).
#define NC 5120
__global__ void topk_stage2(const float* __restrict__ cand_v, const int* __restrict__ cand_p,
                            int* __restrict__ pij, float* __restrict__ ctx_sums,
                            float* __restrict__ out) {
  const int tid = threadIdx.x;
  const int lane = tid & 63, wid = tid >> 6;
  __shared__ float sv[NC];
  __shared__ int sp[NC];
  __shared__ float rv[4];
  __shared__ int rp[4], rq[4];
  __shared__ float selv[20];
  __shared__ int selp[20];

  if (tid < KK) ctx_sums[tid] = 0.0f;

  for (int t = tid; t < NC; t += 256) { sv[t] = cand_v[t]; sp[t] = cand_p[t]; }
  __syncthreads();

  for (int r = 0; r < 20; ++r) {
    float v = -4e30f;
    int p = 0x7fffffff, q = 0;
    for (int t = tid; t < NC; t += 256) {
      float vv = sv[t];
      int pp = sp[t];
      if (better(vv, pp, v, p)) { v = vv; p = pp; q = t; }
    }
    #pragma unroll
    for (int off = 32; off; off >>= 1) {
      float v2 = __shfl_down(v, off);
      int p2 = __shfl_down(p, off);
      int q2 = __shfl_down(q, off);
      if (better(v2, p2, v, p)) { v = v2; p = p2; q = q2; }
    }
    if (lane == 0) { rv[wid] = v; rp[wid] = p; rq[wid] = q; }
    __syncthreads();
    if (tid == 0) {
      #pragma unroll
      for (int t = 1; t < 4; ++t)
        if (better(rv[t], rp[t], v, p)) { v = rv[t]; p = rp[t]; q = rq[t]; }
      selv[r] = v;
      selp[r] = p;
      sv[q] = -3e30f;
    }
    __syncthreads();
  }

  if (tid == 0) {
    int active = 0;
    for (int r = 0; r < 20; ++r) {
      int p = selp[r];
      int i = p >> 8, j = p & 255;
      float s = 1.0f / (1.0f + expf(-selv[r]));
      out[IMP_OFF + r] = s;
      out[PAIR_OFF + 2 * r] = (float)i;
      out[PAIR_OFF + 2 * r + 1] = (float)j;
      if (s > 0.1f) active++;
      pij[r] = i;
      pij[20 + r] = j;
    }
    out[ACT_OFF] = (float)active;
  }
}

// ================= Split path (round 4) =================
// id_ctx: x row in NAMED float4 registers (no arrays -> no scratch, the R3
// bug); weights via uniform s_load (scalar pipe, zero VALU/LDS cost). LDS
// used only for the pair-column gather. h[] touched only with static
// indices via fully-unrolled ACC64.
#define FCH 32
#define NCH (FDIM / FCH)   // 8
#define XSTR 33            // 33 coprime 32 -> conflict-free column gather

#define ACC64(xv_, fi_) { \
  const float* __restrict__ wrow_ = Wc1 + (size_t)(fi_) * HH; \
  _Pragma("unroll") \
  for (int j = 0; j < HH; ++j) h[j] = fmaf((xv_), wrow_[j], h[j]); }

__global__ __launch_bounds__(256, 4) void id_ctx(
    const float* __restrict__ x,
    const float* __restrict__ Wc1, const float* __restrict__ bc1,
    const float* __restrict__ Wc2, const float* __restrict__ bc2,
    const int* __restrict__ pij,
    float* __restrict__ pv_ws, float* __restrict__ ctx_ws,
    float* __restrict__ ctx_sums) {
  __shared__ __align__(16) float xs[256 * XSTR];   // 33792 B
  __shared__ float csum[KK];

  const int tid = threadIdx.x;
  const int b0 = blockIdx.x * 256;
  if (tid < KK) csum[tid] = 0.0f;

  int pcol[2 * KK];
  #pragma unroll
  for (int i = 0; i < 2 * KK; ++i) pcol[i] = __builtin_amdgcn_readfirstlane(pij[i]);

  float h[HH];
  #pragma unroll
  for (int j = 0; j < HH; ++j) h[j] = bc1[j];          // s_loads

  const float* __restrict__ xrow = x + (size_t)(b0 + tid) * FDIM;

  #pragma unroll 1
  for (int c = 0; c < NCH; ++c) {
    const int f0 = c * FCH;
    // own-row chunk: 8 float4 = exactly one 128B line per thread (line-exact)
    const float4 xr0 = *(const float4*)(xrow + f0 +  0);
    const float4 xr1 = *(const float4*)(xrow + f0 +  4);
    const float4 xr2 = *(const float4*)(xrow + f0 +  8);
    const float4 xr3 = *(const float4*)(xrow + f0 + 12);
    const float4 xr4 = *(const float4*)(xrow + f0 + 16);
    const float4 xr5 = *(const float4*)(xrow + f0 + 20);
    const float4 xr6 = *(const float4*)(xrow + f0 + 24);
    const float4 xr7 = *(const float4*)(xrow + f0 + 28);

    __syncthreads();   // previous chunk's gather reads done
    {
      float* __restrict__ d = &xs[tid * XSTR];
      *(float4*)(d +  0) = xr0;  *(float4*)(d +  4) = xr1;
      *(float4*)(d +  8) = xr2;  *(float4*)(d + 12) = xr3;
      *(float4*)(d + 16) = xr4;  *(float4*)(d + 20) = xr5;
      *(float4*)(d + 24) = xr6;  *(float4*)(d + 28) = xr7;
    }
    __syncthreads();   // xs visible

    // pair-column gather (uniform branch; stride-33 column read conflict-free)
    #pragma unroll
    for (int i = 0; i < 2 * KK; ++i) {
      const int cc = pcol[i];
      if (cc >= f0 && cc < f0 + FCH)
        pv_ws[(size_t)i * BTOT + b0 + tid] = xs[tid * XSTR + (cc - f0)];
    }

    // ctx hidden layer: 32x64 FMAs, all operands static-index registers,
    // weights streamed on the scalar pipe
    ACC64(xr0.x, f0 +  0)  ACC64(xr0.y, f0 +  1)
    ACC64(xr0.z, f0 +  2)  ACC64(xr0.w, f0 +  3)
    ACC64(xr1.x, f0 +  4)  ACC64(xr1.y, f0 +  5)
    ACC64(xr1.z, f0 +  6)  ACC64(xr1.w, f0 +  7)
    ACC64(xr2.x, f0 +  8)  ACC64(xr2.y, f0 +  9)
    ACC64(xr2.z, f0 + 10)  ACC64(xr2.w, f0 + 11)
    ACC64(xr3.x, f0 + 12)  ACC64(xr3.y, f0 + 13)
    ACC64(xr3.z, f0 + 14)  ACC64(xr3.w, f0 + 15)
    ACC64(xr4.x, f0 + 16)  ACC64(xr4.y, f0 + 17)
    ACC64(xr4.z, f0 + 18)  ACC64(xr4.w, f0 + 19)
    ACC64(xr5.x, f0 + 20)  ACC64(xr5.y, f0 + 21)
    ACC64(xr5.z, f0 + 22)  ACC64(xr5.w, f0 + 23)
    ACC64(xr6.x, f0 + 24)  ACC64(xr6.y, f0 + 25)
    ACC64(xr6.z, f0 + 26)  ACC64(xr6.w, f0 + 27)
    ACC64(xr7.x, f0 + 28)  ACC64(xr7.y, f0 + 29)
    ACC64(xr7.z, f0 + 30)  ACC64(xr7.w, f0 + 31)
  }

  // ---- ctx output layer: s_load weights, fully static h/ctx ----
  float ctx[KK];
  #pragma unroll
  for (int k = 0; k < KK; ++k) ctx[k] = bc2[k];
  #pragma unroll
  for (int j = 0; j < HH; ++j) {
    const float hj = fmaxf(h[j], 0.0f);
    const float* __restrict__ wrow = Wc2 + j * KK;                  // uniform
    #pragma unroll
    for (int k = 0; k < KK; ++k) ctx[k] = fmaf(hj, wrow[k], ctx[k]);
  }
  #pragma unroll
  for (int k = 0; k < KK; ++k) {
    ctx[k] = 1.0f / (1.0f + expf(-ctx[k]));
    ctx_ws[(size_t)k * BTOT + b0 + tid] = ctx[k];   // coalesced [k][B]
  }

  // ---- ctx mean: wave shuffle -> LDS -> global atomic ----
  const int lane = tid & 63;
  #pragma unroll
  for (int k = 0; k < KK; ++k) {
    float v = ctx[k];
    #pragma unroll
    for (int off = 32; off; off >>= 1) v += __shfl_down(v, off);
    if (lane == 0) atomicAdd(&csum[k], v);
  }
  __syncthreads();
  if (tid < KK) atomicAdd(&ctx_sums[tid], csum[tid]);
}

// id_pair: s_load weights (validated R3: ~355us vs 443 LDS) + 2 samples per
// thread so each uniform weight row feeds 2x the FMA work (hides the per-row
// lgkmcnt drain). No LDS, no barriers. Also absorbs the finalize kernel.
#define SPB 2
__global__ __launch_bounds__(256, 4) void id_pair(
    const float* __restrict__ W1, const float* __restrict__ b1,
    const float* __restrict__ W2, const float* __restrict__ b2,
    const float* __restrict__ W3, const float* __restrict__ b3,
    const float* __restrict__ pv_ws, const float* __restrict__ ctx_ws,
    const float* __restrict__ ctx_sums,
    float* __restrict__ out) {
  const int tid = threadIdx.x;
  const size_t bA = (size_t)blockIdx.x * (256 * SPB) + tid;
  const size_t bB = bA + 256;

  float paA = pv_ws[bA];
  float paB = pv_ws[bB];
  float pbA = pv_ws[(size_t)KK * BTOT + bA];
  float pbB = pv_ws[(size_t)KK * BTOT + bB];
  float cxA = ctx_ws[bA];
  float cxB = ctx_ws[bB];

  #pragma unroll 1
  for (int k = 0; k < KK; ++k) {
    const float* __restrict__ w1a = W1 + (size_t)k * 2 * HH;   // uniform -> s_load
    const float* __restrict__ w1b = w1a + HH;
    const float* __restrict__ b1k = b1 + (size_t)k * HH;
    const float* __restrict__ w2k = W2 + (size_t)k * HH * MM;
    const float* __restrict__ b2k = b2 + (size_t)k * MM;
    const float* __restrict__ w3k = W3 + (size_t)k * MM;

    float h2a[MM], h2b[MM];
    #pragma unroll
    for (int m = 0; m < MM; ++m) { const float bb = b2k[m]; h2a[m] = bb; h2b[m] = bb; }

    #pragma unroll 2
    for (int j = 0; j < HH; ++j) {
      const float wA = w1a[j], wB = w1b[j], bb = b1k[j];
      const float h1a = fmaxf(fmaf(paA, wA, fmaf(pbA, wB, bb)), 0.0f);
      const float h1b = fmaxf(fmaf(paB, wA, fmaf(pbB, wB, bb)), 0.0f);
      const float* __restrict__ wr = w2k + j * MM;
      #pragma unroll
      for (int m = 0; m < MM; ++m) {
        const float w = wr[m];
        h2a[m] = fmaf(h1a, w, h2a[m]);
        h2b[m] = fmaf(h1b, w, h2b[m]);
      }
    }

    float oA = b3[k], oB = b3[k];
    #pragma unroll
    for (int m = 0; m < MM; ++m) {
      const float w = w3k[m];
      oA = fmaf(fmaxf(h2a[m], 0.0f), w, oA);
      oB = fmaf(fmaxf(h2b[m], 0.0f), w, oB);
    }

    const float rA = oA * cxA;
    const float rB = oB * cxB;
    if (k + 1 < KK) {      // prefetch next k's per-sample inputs (vmcnt-hidden)
      paA = pv_ws[(size_t)(k + 1) * BTOT + bA];
      paB = pv_ws[(size_t)(k + 1) * BTOT + bB];
      pbA = pv_ws[(size_t)(KK + k + 1) * BTOT + bA];
      pbB = pv_ws[(size_t)(KK + k + 1) * BTOT + bB];
      cxA = ctx_ws[(size_t)(k + 1) * BTOT + bA];
      cxB = ctx_ws[(size_t)(k + 1) * BTOT + bB];
    }
    out[bA * KK + k] = rA;
    out[bB * KK + k] = rB;
  }

  // finalize folded in: CWM depends only on ctx_sums (complete before this
  // kernel started), so block 0 can write it
  if (blockIdx.x == 0 && tid < KK)
    out[CWM_OFF + tid] = ctx_sums[tid] * (1.0f / (float)BTOT);
}

// ================= Fallback fused kernel (round-1, known-passing) =================
#define FCHF 32
#define NCHUNKF (FDIM / FCHF)
#define XSTRF 33

__global__ __launch_bounds__(256, 3) void id_main_fused(
    const float* __restrict__ x,
    const float* __restrict__ Wc1, const float* __restrict__ bc1,
    const float* __restrict__ Wc2, const float* __restrict__ bc2,
    const float* __restrict__ W1, const float* __restrict__ b1,
    const float* __restrict__ W2, const float* __restrict__ b2,
    const float* __restrict__ W3, const float* __restrict__ b3,
    const int* __restrict__ pij,
    float* __restrict__ ctx_sums,
    float* __restrict__ out) {
  __shared__ __align__(16) float xs[256 * XSTRF];
  __shared__ float csum[KK];

  const int tid = threadIdx.x;
  const int b0 = blockIdx.x * 256;
  if (tid < KK) csum[tid] = 0.0f;

  int pcol[2 * KK];
  #pragma unroll
  for (int i = 0; i < 2 * KK; ++i) pcol[i] = __builtin_amdgcn_readfirstlane(pij[i]);

  float h[HH];
  #pragma unroll
  for (int j = 0; j < HH; ++j) h[j] = bc1[j];
  float pv[2 * KK];
  #pragma unroll
  for (int i = 0; i < 2 * KK; ++i) pv[i] = 0.0f;

  const int srow = tid >> 3;
  const int quad = tid & 7;
  const float* __restrict__ xrow_lds = &xs[tid * XSTRF];

  #pragma unroll 1
  for (int c = 0; c < NCHUNKF; ++c) {
    const int f0 = c * FCHF;
    __syncthreads();
    const float* __restrict__ xg = x + (size_t)(b0 + srow) * FDIM + f0 + quad * 4;
    #pragma unroll
    for (int r = 0; r < 8; ++r) {
      const float4 v = *(const float4*)(xg + (size_t)r * 32 * FDIM);
      float* d = &xs[(srow + r * 32) * XSTRF + quad * 4];
      d[0] = v.x; d[1] = v.y; d[2] = v.z; d[3] = v.w;
    }
    __syncthreads();
    #pragma unroll 2
    for (int f = 0; f < FCHF; ++f) {
      const float xv = xrow_lds[f];
      const float* __restrict__ w0 = Wc1 + (size_t)(f0 + f) * HH;
      #pragma unroll
      for (int j = 0; j < HH; ++j) h[j] = fmaf(xv, w0[j], h[j]);
    }
    #pragma unroll
    for (int i = 0; i < 2 * KK; ++i) {
      const int cc = pcol[i];
      if (cc >= f0 && cc < f0 + FCHF) pv[i] = xrow_lds[cc - f0];
    }
  }

  float ctx[KK];
  #pragma unroll
  for (int k = 0; k < KK; ++k) ctx[k] = bc2[k];
  #pragma unroll
  for (int j = 0; j < HH; ++j) {
    const float hj = fmaxf(h[j], 0.0f);
    const float* __restrict__ wr = Wc2 + j * KK;
    #pragma unroll
    for (int k = 0; k < KK; ++k) ctx[k] = fmaf(hj, wr[k], ctx[k]);
  }
  #pragma unroll
  for (int k = 0; k < KK; ++k) ctx[k] = 1.0f / (1.0f + expf(-ctx[k]));

  __syncthreads();
  float* __restrict__ so = xs;

  #pragma unroll 1
  for (int k = 0; k < KK; ++k) {
    float pa = 0.0f, pb = 0.0f;
    #pragma unroll
    for (int i = 0; i < KK; ++i)
      if (k == i) { pa = pv[i]; pb = pv[KK + i]; }

    const float* __restrict__ w1k = W1 + (size_t)k * 2 * HH;
    const float* __restrict__ b1k = b1 + (size_t)k * HH;
    const float* __restrict__ w2k = W2 + (size_t)k * HH * MM;
    const float* __restrict__ b2k = b2 + (size_t)k * MM;

    float h2[MM];
    #pragma unroll
    for (int m = 0; m < MM; ++m) h2[m] = b2k[m];

    #pragma unroll 2
    for (int j = 0; j < HH; ++j) {
      const float h1j = fmaxf(fmaf(pa, w1k[j], fmaf(pb, w1k[HH + j], b1k[j])), 0.0f);
      const float* __restrict__ wr = w2k + j * MM;
      #pragma unroll
      for (int m = 0; m < MM; ++m) h2[m] = fmaf(h1j, wr[m], h2[m]);
    }

    const float* __restrict__ w3k = W3 + (size_t)k * MM;
    float o = b3[k];
    #pragma unroll
    for (int m = 0; m < MM; ++m) o = fmaf(fmaxf(h2[m], 0.0f), w3k[m], o);

    so[tid * KK + k] = o;
  }

  #pragma unroll
  for (int k = 0; k < KK; ++k) so[tid * KK + k] *= ctx[k];

  const int lane = tid & 63;
  #pragma unroll
  for (int k = 0; k < KK; ++k) {
    float v = ctx[k];
    #pragma unroll
    for (int off = 32; off; off >>= 1) v += __shfl_down(v, off);
    if (lane == 0) atomicAdd(&csum[k], v);
  }
  __syncthreads();
  if (tid < KK) atomicAdd(&ctx_sums[tid], csum[tid]);

  const float4* __restrict__ sof = (const float4*)so;
  float4* __restrict__ og = (float4*)(out + (size_t)b0 * KK);
  #pragma unroll
  for (int i = 0; i < 5; ++i) og[tid + i * 256] = sof[tid + i * 256];
}

__global__ void id_finalize(const float* __restrict__ ctx_sums, float* __restrict__ out) {
  const int k = threadIdx.x;
  if (k < KK) out[CWM_OFF + k] = ctx_sums[k] * (1.0f / (float)BTOT);
}

extern "C" void kernel_launch(void* const* d_in, const int* in_sizes, int n_in,
                              void* d_out, int out_size, void* d_ws, size_t ws_size,
                              hipStream_t stream) {
  const float* x   = (const float*)d_in[0];
  const float* iw  = (const float*)d_in[1];
  const float* Wc1 = (const float*)d_in[2];
  const float* bc1 = (const float*)d_in[3];
  const float* Wc2 = (const float*)d_in[4];
  const float* bc2 = (const float*)d_in[5];
  const float* W1  = (const float*)d_in[6];
  const float* b1  = (const float*)d_in[7];
  const float* W2  = (const float*)d_in[8];
  const float* b2  = (const float*)d_in[9];
  const float* W3  = (const float*)d_in[10];
  const float* b3  = (const float*)d_in[11];
  float* out = (float*)d_out;

  float* wsf    = (float*)d_ws;
  float* cand_v = wsf;                  // 5120 floats
  int*   cand_p = (int*)(wsf + 5120);   // 5120 ints
  int*   pij    = (int*)(wsf + 10240);  // 40 ints
  float* csums  = wsf + 10280;          // 20 floats
  float* pv_ws  = wsf + 10304;          // 40*BTOT floats
  float* ctx_ws = wsf + 10304 + (size_t)2 * KK * BTOT;  // 20*BTOT floats
  const size_t need_bytes = ((size_t)10304 + (size_t)3 * KK * BTOT) * sizeof(float); // ~63 MB

  topk_stage1<<<256, 256, 0, stream>>>(iw, cand_v, cand_p);
  topk_stage2<<<1, 256, 0, stream>>>(cand_v, cand_p, pij, csums, out);
  if (ws_size >= need_bytes) {
    id_ctx<<<BTOT / 256, 256, 0, stream>>>(x, Wc1, bc1, Wc2, bc2, pij,
                                           pv_ws, ctx_ws, csums);
    id_pair<<<BTOT / (256 * SPB), 256, 0, stream>>>(W1, b1, W2, b2, W3, b3,
                                                    pv_ws, ctx_ws, csums, out);
  } else {
    id_main_fused<<<BTOT / 256, 256, 0, stream>>>(x, Wc1, bc1, Wc2, bc2,
                                                  W1, b1, W2, b2, W3, b3,
                                                  pij, csums, out);
    id_finalize<<<1, 64, 0, stream>>>(csums, out);
  }
}